// Round 2
// baseline (19773.209 us; speedup 1.0000x reference)
//
#include <hip/hip_runtime.h>

#define DEVFN __device__ __forceinline__

constexpr int V=32000, E=512, H=512, B=16, K=8, S=50, T=40, N=128;
constexpr int SOS=2, EOS=3, UNK=0, PAD=1, MIN_LEN=3;
constexpr float DD=0.1f;
constexpr float FNEG=-1e20f;

constexpr long long PROBS_ELEMS = 163840000LL; // T*N*V
constexpr int TOK_OUT_OFF = 163840000;
constexpr int BS_OUT_OFF  = 163845120;

// scratch offsets (floats) inside d_out's probs region (re-zeroed at the end)
constexpr int LOGITS_O = 0;          // N*V = 4,096,000
constexpr int WTOUT_O  = 4200000;    // 512*32000
constexpr int WTEIH_O  = 20600000;   // 512*1536
constexpr int WTEHH_O  = 21400000;
constexpr int WTDIH_O  = 22200000;
constexpr int WTDHH_O  = 23000000;
constexpr int WTATT_O  = 23800000;   // 512*512
constexpr int WTCMB_O  = 24100000;   // 1024*512
constexpr int WTBRG_O  = 24700000;   // 512*512
constexpr int ENC_O    = 25000000;   // S*B*H
constexpr int HST_O    = 25500000;   // 2*B*H
constexpr int HID_O    = 25520000;   // N*H
constexpr int HNEW_O   = 25600000;   // N*H
constexpr int CTX_O    = 25680000;   // N*H
constexpr int OVEC_O   = 25760000;   // N*H
constexpr int QVEC_O   = 25840000;   // N*H
constexpr int TKSC_O   = 25920000;   // N*K
constexpr int TKIX_O   = 25930000;   // N*K ints
constexpr int TOK0_O   = 25940000;   // T*N ints
constexpr int TOK1_O   = 25950000;
constexpr int BS0_O    = 25960000;   // T*N floats
constexpr int BS1_O    = 25970000;
constexpr int END_O    = 25980000;   // N ints
constexpr int LTOK_O   = 25990000;   // N ints
constexpr int DIAG_O   = 25995000;   // 1 int

DEVFN float sigm(float x){ return 1.0f/(1.0f + expf(-x)); }

// ---------------- transpose: in[R][C] -> out[C][R] ----------------
__global__ void tr_k(const float* __restrict__ in, float* __restrict__ out, int R, int C){
  __shared__ float t[32][33];
  int bx = blockIdx.x, by = blockIdx.y;
  int x = threadIdx.x & 31, y0 = threadIdx.x >> 5;
  for (int yy = y0; yy < 32; yy += 8){
    t[yy][x] = in[(long long)(by*32+yy)*C + bx*32 + x];
  }
  __syncthreads();
  for (int yy = y0; yy < 32; yy += 8){
    out[(long long)(bx*32+yy)*R + by*32 + x] = t[x][yy];
  }
}

// ---------------- init ----------------
__global__ void init_k(float* sc){
  int idx = blockIdx.x*256 + threadIdx.x;
  int* tok0 = (int*)(sc + TOK0_O);
  float* bs0 = sc + BS0_O;
  if (idx < T*N){
    tok0[idx] = (idx < N) ? SOS : 0;
    bs0[idx]  = (idx < N && (idx & 7)) ? FNEG : 0.0f;
  }
  if (idx < N){
    ((int*)(sc + END_O))[idx] = 0;
    ((int*)(sc + LTOK_O))[idx] = SOS;
  }
  if (idx < 2*B*H) sc[HST_O + idx] = 0.0f;
  if (idx == 0) ((int*)(sc + DIAG_O))[0] = 0;
}

// ---------------- encoder one step ----------------
__global__ __launch_bounds__(256) void enc_k(const int* __restrict__ src, const int* __restrict__ srclen,
                      const float* __restrict__ embed,
                      const float* __restrict__ wtih, const float* __restrict__ wthh,
                      const float* __restrict__ bih, const float* __restrict__ bhh,
                      float* sc, int t){
  int b = blockIdx.x;
  int i = blockIdx.y*256 + threadIdx.x;
  __shared__ __align__(16) float e[512];
  __shared__ __align__(16) float hp[512];
  const float* hsrc = sc + HST_O + (t&1)*B*H + b*H;
  float* hdst = sc + HST_O + (((t&1)^1))*B*H + b*H;
  int tok = src[t*B + b];
  {
    int tid = threadIdx.x;
    ((float2*)e)[tid]  = ((const float2*)(embed + (long long)tok*E))[tid];
    ((float2*)hp)[tid] = ((const float2*)hsrc)[tid];
  }
  __syncthreads();
  float ar=0,az=0,an=0,hr=0,hz=0,hn=0;
  for (int k=0;k<512;k++){
    float ev = e[k], hv = hp[k];
    const float* wi = wtih + (long long)k*1536;
    const float* wh = wthh + (long long)k*1536;
    ar += ev*wi[i];      az += ev*wi[512+i];  an += ev*wi[1024+i];
    hr += hv*wh[i];      hz += hv*wh[512+i];  hn += hv*wh[1024+i];
  }
  float r = sigm(ar + bih[i] + hr + bhh[i]);
  float z = sigm(az + bih[512+i] + hz + bhh[512+i]);
  float nn = tanhf(an + bih[1024+i] + r*(hn + bhh[1024+i]));
  float hnew = (1.0f - z)*nn + z*hp[i];
  float hout = (t < srclen[b]) ? hnew : hp[i];
  hdst[i] = hout;
  sc[ENC_O + ((long long)t*B + b)*H + i] = hout;
}

// ---------------- bridge + repeat K ----------------
__global__ __launch_bounds__(256) void bridge_k(const float* __restrict__ wtb, const float* __restrict__ bb, float* sc){
  int b = blockIdx.x; int tid = threadIdx.x;
  __shared__ __align__(16) float hf[512];
  const float* hsrc = sc + HST_O + (S&1)*B*H + b*H;
  ((float2*)hf)[tid] = ((const float2*)hsrc)[tid];
  __syncthreads();
  for (int ii=0; ii<2; ii++){
    int i = tid + ii*256;
    float acc = bb[i];
    for (int k=0;k<512;k++) acc += hf[k]*wtb[(long long)k*512 + i];
    float hb = tanhf(acc);
    for (int q=0;q<K;q++) sc[HID_O + ((long long)(b*K+q))*H + i] = hb;
  }
}

// ---------------- decoder GRU (all beams tiled) ----------------
__global__ __launch_bounds__(256) void grudec_k(const float* __restrict__ embed,
     const float* __restrict__ wtih, const float* __restrict__ wthh,
     const float* __restrict__ bih, const float* __restrict__ bhh, float* sc){
  int il = threadIdx.x & 63, sub = threadIdx.x >> 6;
  int i = blockIdx.x*64 + il;
  int nb = blockIdx.y*8;
  __shared__ __align__(16) float e8[8][512];
  __shared__ __align__(16) float hp8[8][512];
  const int* ltok = (const int*)(sc + LTOK_O);
  for (int u = threadIdx.x; u < 8*128; u += 256){
    int r = u >> 7, c = u & 127;
    ((float4*)e8[r])[c]  = ((const float4*)(embed + (long long)ltok[nb+r]*E))[c];
    ((float4*)hp8[r])[c] = ((const float4*)(sc + HID_O + (long long)(nb+r)*H))[c];
  }
  __syncthreads();
  int n0 = sub*2, n1 = sub*2+1;
  float a0r=0,a0z=0,a0n=0,h0r=0,h0z=0,h0n=0;
  float a1r=0,a1z=0,a1n=0,h1r=0,h1z=0,h1n=0;
  for (int k=0;k<512;k++){
    const float* wi = wtih + (long long)k*1536;
    const float* wh = wthh + (long long)k*1536;
    float wr=wi[i], wz=wi[512+i], wn=wi[1024+i];
    float ur=wh[i], uz=wh[512+i], un=wh[1024+i];
    float e0=e8[n0][k], e1=e8[n1][k], p0=hp8[n0][k], p1=hp8[n1][k];
    a0r+=e0*wr; a0z+=e0*wz; a0n+=e0*wn; h0r+=p0*ur; h0z+=p0*uz; h0n+=p0*un;
    a1r+=e1*wr; a1z+=e1*wz; a1n+=e1*wn; h1r+=p1*ur; h1z+=p1*uz; h1n+=p1*un;
  }
  float br=bih[i], bz=bih[512+i], bn=bih[1024+i];
  float cr=bhh[i], cz=bhh[512+i], cn=bhh[1024+i];
  {
    float r = sigm(a0r+br+h0r+cr);
    float z = sigm(a0z+bz+h0z+cz);
    float nn = tanhf(a0n+bn + r*(h0n+cn));
    sc[HNEW_O + (long long)(nb+n0)*H + i] = (1.0f-z)*nn + z*hp8[n0][i];
  }
  {
    float r = sigm(a1r+br+h1r+cr);
    float z = sigm(a1z+bz+h1z+cz);
    float nn = tanhf(a1n+bn + r*(h1n+cn));
    sc[HNEW_O + (long long)(nb+n1)*H + i] = (1.0f-z)*nn + z*hp8[n1][i];
  }
}

// ---------------- q = h_new @ attn_W^T ----------------
__global__ __launch_bounds__(256) void qgemm_k(const float* __restrict__ wta, float* sc){
  int il = threadIdx.x & 63, sub = threadIdx.x >> 6;
  int i = blockIdx.x*64 + il;
  int nb = blockIdx.y*8;
  __shared__ __align__(16) float hn8[8][512];
  for (int u = threadIdx.x; u < 8*128; u += 256){
    int r = u>>7, c = u&127;
    ((float4*)hn8[r])[c] = ((const float4*)(sc + HNEW_O + (long long)(nb+r)*H))[c];
  }
  __syncthreads();
  int n0 = sub*2, n1 = n0+1;
  float a0=0, a1=0;
  for (int k=0;k<512;k++){
    float w = wta[(long long)k*512 + i];
    a0 += hn8[n0][k]*w; a1 += hn8[n1][k]*w;
  }
  sc[QVEC_O + (long long)(nb+n0)*H + i] = a0;
  sc[QVEC_O + (long long)(nb+n1)*H + i] = a1;
}

// ---------------- attention scores/softmax/ctx per beam ----------------
__global__ __launch_bounds__(256) void att_k(const int* __restrict__ srclen, float* sc){
  int n = blockIdx.x; int g = n >> 3;
  int tid = threadIdx.x, lane = tid & 63, wave = tid >> 6;
  __shared__ __align__(16) float ql[512];
  __shared__ float al[64];
  if (tid < 128) ((float4*)ql)[tid] = ((const float4*)(sc + QVEC_O + (long long)n*H))[tid];
  __syncthreads();
  const float* enc = sc + ENC_O;
  for (int s = wave; s < S; s += 4){
    const float* er = enc + ((long long)s*B + g)*H;
    float p = 0;
    #pragma unroll
    for (int j=0;j<8;j++) p += ql[lane + 64*j]*er[lane + 64*j];
    #pragma unroll
    for (int off=32; off; off>>=1) p += __shfl_xor(p, off, 64);
    if (lane==0) al[s] = p;
  }
  __syncthreads();
  if (wave==0){
    int len = srclen[g];
    float v = (lane < S && lane < len) ? al[lane] : -1e9f;
    float m = v;
    #pragma unroll
    for (int off=32; off; off>>=1) m = fmaxf(m, __shfl_xor(m, off, 64));
    float ee = (lane < S) ? expf(v - m) : 0.0f;
    float ssum = ee;
    #pragma unroll
    for (int off=32; off; off>>=1) ssum += __shfl_xor(ssum, off, 64);
    if (lane < S) al[lane] = ee/ssum;
  }
  __syncthreads();
  for (int ii=0; ii<2; ii++){
    int i = tid + ii*256;
    float acc = 0;
    for (int s=0;s<S;s++) acc += al[s]*enc[((long long)s*B+g)*H + i];
    sc[CTX_O + (long long)n*H + i] = acc;
  }
}

// ---------------- o = tanh([h,ctx] @ comb_W^T + b) ----------------
__global__ __launch_bounds__(256) void comb_k(const float* __restrict__ wtc, const float* __restrict__ cb, float* sc){
  int il = threadIdx.x & 63, sub = threadIdx.x >> 6;
  int i = blockIdx.x*64 + il;
  int nb = blockIdx.y*8;
  __shared__ __align__(16) float hn8[8][512];
  __shared__ __align__(16) float cx8[8][512];
  for (int u = threadIdx.x; u < 8*128; u += 256){
    int r = u>>7, c = u&127;
    ((float4*)hn8[r])[c] = ((const float4*)(sc + HNEW_O + (long long)(nb+r)*H))[c];
    ((float4*)cx8[r])[c] = ((const float4*)(sc + CTX_O + (long long)(nb+r)*H))[c];
  }
  __syncthreads();
  int n0 = sub*2, n1 = n0+1;
  float a0=cb[i], a1=cb[i];
  for (int k=0;k<512;k++){
    float w = wtc[(long long)k*512 + i];
    a0 += hn8[n0][k]*w; a1 += hn8[n1][k]*w;
  }
  for (int k=0;k<512;k++){
    float w = wtc[(long long)(512+k)*512 + i];
    a0 += cx8[n0][k]*w; a1 += cx8[n1][k]*w;
  }
  sc[OVEC_O + (long long)(nb+n0)*H + i] = tanhf(a0);
  sc[OVEC_O + (long long)(nb+n1)*H + i] = tanhf(a1);
}

// ---------------- logits = o @ out_W^T + out_b (16 rows/block, 32KB LDS) ----------------
__global__ __launch_bounds__(256) void logits_k(const float* __restrict__ wto, const float* __restrict__ ob, float* sc){
  int lane = threadIdx.x & 63, bg = threadIdx.x >> 6;
  int v = blockIdx.x*256 + lane*4;
  int nb = blockIdx.y*16 + bg*4;
  __shared__ __align__(16) float o16[16][512];
  for (int u = threadIdx.x; u < 16*128; u += 256){
    int r = u>>7, c = u&127;
    ((float4*)o16[r])[c] = ((const float4*)(sc + OVEC_O + (long long)(blockIdx.y*16 + r)*H))[c];
  }
  __syncthreads();
  float acc[4][4] = {};
  for (int k=0;k<512;k++){
    float4 w = *((const float4*)(wto + (long long)k*V + v));
    #pragma unroll
    for (int j=0;j<4;j++){
      float o = o16[bg*4+j][k];
      acc[j][0] += o*w.x; acc[j][1] += o*w.y; acc[j][2] += o*w.z; acc[j][3] += o*w.w;
    }
  }
  float4 bbv = *((const float4*)(ob + v));
  #pragma unroll
  for (int j=0;j<4;j++){
    float4 r;
    r.x = acc[j][0]+bbv.x; r.y = acc[j][1]+bbv.y; r.z = acc[j][2]+bbv.z; r.w = acc[j][3]+bbv.w;
    *((float4*)(sc + LOGITS_O + (long long)(nb+j)*V + v)) = r;
  }
}

// ---------------- per-row logsumexp + top-8 (stable, lower index first) ----------------
__global__ __launch_bounds__(256) void topk_k(float* sc, int t){
  int n = blockIdx.x, tid = threadIdx.x;
  const float4* row4 = (const float4*)(sc + LOGITS_O + (long long)n*V);
  __shared__ float rv[256]; __shared__ int ri[256];
  float lm = -INFINITY;
  for (int u = tid; u < V/4; u += 256){
    float4 x = row4[u];
    lm = fmaxf(lm, fmaxf(fmaxf(x.x,x.y), fmaxf(x.z,x.w)));
  }
  rv[tid] = lm; __syncthreads();
  for (int s2=128; s2; s2>>=1){ if (tid<s2) rv[tid]=fmaxf(rv[tid],rv[tid+s2]); __syncthreads(); }
  float rmax = rv[0]; __syncthreads();
  float ls = 0;
  for (int u = tid; u < V/4; u += 256){
    float4 x = row4[u];
    ls += expf(x.x-rmax)+expf(x.y-rmax)+expf(x.z-rmax)+expf(x.w-rmax);
  }
  rv[tid] = ls; __syncthreads();
  for (int s2=128; s2; s2>>=1){ if (tid<s2) rv[tid]+=rv[tid+s2]; __syncthreads(); }
  float lsum = logf(rv[0]); __syncthreads();
  float pv = INFINITY; int pi = -1;
  for (int j=0;j<8;j++){
    float bv = -INFINITY; int bi = V;
    for (int u = tid; u < V/4; u += 256){
      float4 x = row4[u];
      #pragma unroll
      for (int c=0;c<4;c++){
        int idx = u*4+c;
        float val = (c==0)?x.x:(c==1)?x.y:(c==2)?x.z:x.w;
        if (idx==UNK) val = -INFINITY;
        if (idx==EOS && t<=MIN_LEN) val = -INFINITY;
        bool ok = (val < pv) || (val == pv && idx > pi);
        if (ok && (val > bv || (val == bv && idx < bi))){ bv = val; bi = idx; }
      }
    }
    rv[tid]=bv; ri[tid]=bi; __syncthreads();
    for (int s2=128; s2; s2>>=1){
      if (tid<s2){
        if (rv[tid+s2] > rv[tid] || (rv[tid+s2]==rv[tid] && ri[tid+s2]<ri[tid])){
          rv[tid]=rv[tid+s2]; ri[tid]=ri[tid+s2];
        }
      }
      __syncthreads();
    }
    pv = rv[0]; pi = ri[0];
    if (tid==0){
      sc[TKSC_O + n*8 + j] = (pv - rmax) - lsum;
      ((int*)(sc + TKIX_O))[n*8 + j] = pi;
    }
    __syncthreads();
  }
}

// ---------------- beam bookkeeping (serial on lane 0 of one wave per batch) ----------------
__global__ __launch_bounds__(64) void beam_k(float* sc, int t){
  int b = blockIdx.x, lane = threadIdx.x;
  const float* tksc = sc + TKSC_O;
  const int* tkix = (const int*)(sc + TKIX_O);
  int* endp = (int*)(sc + END_O);
  int* ltok = (int*)(sc + LTOK_O);
  const int* tokc; int* tokn; const float* bsc; float* bsn;
  if (t & 1){ tokc=(const int*)(sc+TOK0_O); tokn=(int*)(sc+TOK1_O); bsc=sc+BS0_O; bsn=sc+BS1_O; }
  else      { tokc=(const int*)(sc+TOK1_O); tokn=(int*)(sc+TOK0_O); bsc=sc+BS1_O; bsn=sc+BS0_O; }
  __shared__ int selp[8]; __shared__ int newtok[8]; __shared__ float newsc[8]; __shared__ int newend[8];
  if (lane == 0){
    float tot[64]; float cur[64]; int tix[64];
    for (int k=0;k<8;k++){
      float tp = 0;
      for (int u=0;u<T;u++) tp += bsc[u*N + b*8 + k];
      int ek = endp[b*8+k];
      for (int j=0;j<8;j++){
        float scv = tksc[(b*8+k)*8 + j];
        if (t > 1) scv -= DD * (float)j;
        float fin = ek ? (-scv + (j==0 ? 0.0f : FNEG)) : 0.0f;
        tot[k*8+j] = (scv + tp) + fin;   // ((tk_sc+total)+fin) as in ref
        cur[k*8+j] = scv + fin;
        tix[k*8+j] = tkix[(b*8+k)*8 + j];
      }
    }
    for (int q=0;q<8;q++){
      int best = 0; float bv = tot[0];
      for (int c=1;c<64;c++){
        if (tot[c] > bv){ bv = tot[c]; best = c; }   // strict > keeps lowest index on ties
      }
      int p = best >> 3;
      int en = endp[b*8+p];
      int tk2 = tix[best];
      int lt = en ? PAD : tk2;
      selp[q] = p;
      newtok[q] = lt;
      newsc[q] = (lt != PAD) ? cur[best] : 0.0f;
      newend[q] = (en || lt == EOS) ? 1 : 0;
      tot[best] = -INFINITY;
    }
  }
  __syncthreads();
  for (int u = lane; u < T*8; u += 64){
    int tp2 = u >> 3, jp = u & 7;
    int p = selp[jp];
    tokn[tp2*N + b*8 + jp] = tokc[tp2*N + b*8 + p];
    bsn[tp2*N + b*8 + jp]  = bsc[tp2*N + b*8 + p];
  }
  __syncthreads();
  if (lane < 8){
    tokn[t*N + b*8 + lane] = newtok[lane];
    bsn[t*N + b*8 + lane]  = newsc[lane];
    ltok[b*8+lane] = newtok[lane];
    endp[b*8+lane] = newend[lane];
  }
  // hidden = hidden[flat_offsets] (beam-0 broadcast of h_new within group)
  const float4* hsrc = (const float4*)(sc + HNEW_O + (long long)(b*8)*H);
  float4* hdst = (float4*)(sc + HID_O + (long long)(b*8)*H);
  for (int u = lane; u < 8*128; u += 64){
    int jp = u >> 7, c = u & 127;
    hdst[jp*128 + c] = hsrc[c];
  }
}

// ---------------- diagnostics (read-only except DIAG_O) ----------------
__global__ __launch_bounds__(256) void diag_net_k(const int* srclen,
    const float* embed, const float* dWih, const float* dWhh, const float* dbih, const float* dbhh,
    const float* attW, const float* cmbW, const float* cmbb, const float* outW, const float* outb,
    float* sc, int shift){
  int tid = threadIdx.x; int lane = tid & 63; int wv = tid >> 6;
  __shared__ int codesh;
  __shared__ float qd[512];
  __shared__ float aw[64];
  if (tid == 0) codesh = 0;
  __syncthreads();
  int code = 0;
  for (int u = tid; u < N*H; u += 256){
    float v = sc[HNEW_O + u];
    if (!(v==v) || fabsf(v) > 1.0001f) code |= 1;
    float o = sc[OVEC_O + u];
    if (!(o==o) || fabsf(o) > 1.0001f) code |= 2;
    float c = sc[CTX_O + u];
    if (!(c==c) || fabsf(c) > 1.0001f) code |= 4;
  }
  for (int u = tid; u < S*B*H; u += 256){
    float v = sc[ENC_O + u];
    if (!(v==v) || fabsf(v) > 1.0001f) code |= 8;
  }
  for (int u = tid; u < 8192; u += 256){
    int k = (u*7) & 511;
    long long vv = ((long long)u*1237) % V;
    if (sc[WTOUT_O + (long long)k*V + vv] != outW[vv*512 + k]) code |= 16;
  }
  if (wv == 0){   // GRU recompute, row 0, i in {1,257}
    int ltk = ((const int*)(sc+LTOK_O))[0];
    const float* e = embed + (long long)ltk*E;
    const float* hp = sc + HID_O;
    for (int rep=0; rep<2; rep++){
      int i0 = rep ? 257 : 1;
      float gr=0,gz=0,gn=0,hr=0,hz=0,hn=0;
      for (int k = lane; k < 512; k += 64){
        float ev=e[k], hv=hp[k];
        gr += ev*dWih[(long long)i0*512+k]; gz += ev*dWih[(long long)(512+i0)*512+k]; gn += ev*dWih[(long long)(1024+i0)*512+k];
        hr += hv*dWhh[(long long)i0*512+k]; hz += hv*dWhh[(long long)(512+i0)*512+k]; hn += hv*dWhh[(long long)(1024+i0)*512+k];
      }
      for (int off=32; off; off>>=1){
        gr+=__shfl_xor(gr,off,64); gz+=__shfl_xor(gz,off,64); gn+=__shfl_xor(gn,off,64);
        hr+=__shfl_xor(hr,off,64); hz+=__shfl_xor(hz,off,64); hn+=__shfl_xor(hn,off,64);
      }
      if (lane==0){
        float r = sigm(gr + dbih[i0] + hr + dbhh[i0]);
        float z = sigm(gz + dbih[512+i0] + hz + dbhh[512+i0]);
        float nn = tanhf(gn + dbih[1024+i0] + r*(hn + dbhh[1024+i0]));
        float href = (1.0f-z)*nn + z*hp[i0];
        if (fabsf(href - sc[HNEW_O + i0]) > 2e-3f) code |= 32;
      }
    }
  }
  if (wv == 1){   // comb recompute, row 0, i in {3,300}
    const float* h = sc + HNEW_O; const float* cx = sc + CTX_O;
    for (int rep=0; rep<2; rep++){
      int i0 = rep ? 300 : 3;
      float a = 0;
      for (int k = lane; k < 512; k += 64){
        a += h[k]*cmbW[(long long)i0*1024 + k] + cx[k]*cmbW[(long long)i0*1024 + 512 + k];
      }
      for (int off=32; off; off>>=1) a += __shfl_xor(a,off,64);
      if (lane==0){
        float oref = tanhf(a + cmbb[i0]);
        if (fabsf(oref - sc[OVEC_O + i0]) > 2e-3f) code |= 64;
      }
    }
  }
  if (wv == 2){   // logits recompute, row 0, v in {5,12345,31999}
    const float* o = sc + OVEC_O;
    int vs0[3] = {5, 12345, 31999};
    for (int rep=0; rep<3; rep++){
      long long v0 = vs0[rep];
      float a = 0;
      for (int k = lane; k < 512; k += 64) a += o[k]*outW[v0*512 + k];
      for (int off=32; off; off>>=1) a += __shfl_xor(a,off,64);
      if (lane==0){
        float lref = a + outb[v0];
        if (fabsf(lref - sc[LOGITS_O + v0]) > 2e-3f) code |= 128;
      }
    }
  }
  __syncthreads();
  {  // attention recompute for row 0: q then scores then ctx[7]
    const float* h = sc + HNEW_O;
    for (int ii=0; ii<2; ii++){
      int i0 = tid + ii*256;
      float a=0;
      for (int k=0;k<512;k++) a += h[k]*attW[(long long)i0*512+k];
      qd[i0] = a;
    }
  }
  __syncthreads();
  if (wv == 3 && lane < S){
    float p=0;
    for (int i=0;i<512;i++) p += qd[i]*sc[ENC_O + ((long long)lane*B + 0)*H + i];
    aw[lane] = p;
  }
  __syncthreads();
  if (tid == 0){
    int len = srclen[0];
    float m = -1e30f;
    for (int s=0;s<S;s++){ float v2 = (s<len)? aw[s] : -1e9f; aw[s]=v2; if (v2>m) m=v2; }
    float ss=0;
    for (int s=0;s<S;s++){ aw[s] = expf(aw[s]-m); ss += aw[s]; }
    float cref = 0;
    for (int s=0;s<S;s++) cref += (aw[s]/ss)*sc[ENC_O + ((long long)s*B+0)*H + 7];
    if (fabsf(cref - sc[CTX_O + 7]) > 2e-3f) code |= 256;
  }
  atomicOr(&codesh, code);
  __syncthreads();
  if (tid == 0 && codesh){
    atomicOr((int*)(sc + DIAG_O), codesh << shift);
  }
}

__global__ __launch_bounds__(256) void diag_topk_k(float* sc, int t, int shift){
  int tid = threadIdx.x;
  __shared__ float red[256]; __shared__ int redi[256];
  const float* row = sc + LOGITS_O;  // n=0
  float lm = -INFINITY;
  for (int v = tid; v < V; v += 256) lm = fmaxf(lm, row[v]);
  red[tid]=lm; __syncthreads();
  for (int s2=128; s2; s2>>=1){ if (tid<s2) red[tid]=fmaxf(red[tid],red[tid+s2]); __syncthreads(); }
  float rmax = red[0]; __syncthreads();
  float ls=0;
  for (int v = tid; v < V; v += 256) ls += expf(row[v]-rmax);
  red[tid]=ls; __syncthreads();
  for (int s2=128; s2; s2>>=1){ if (tid<s2) red[tid]+=red[tid+s2]; __syncthreads(); }
  float lsum = logf(red[0]); __syncthreads();
  int i0 = ((const int*)(sc+TKIX_O))[0];
  int i7 = ((const int*)(sc+TKIX_O))[7];
  float v0 = row[i0], v7 = row[i7];
  int cg0=0, cg7=0;
  for (int v = tid; v < V; v += 256){
    bool masked = (v==UNK) || (v==EOS && t<=MIN_LEN);
    if (!masked){
      float x = row[v];
      if (x > v0 || (x == v0 && v < i0)) cg0++;
      if (x > v7) cg7++;
    }
  }
  redi[tid]=cg0; __syncthreads();
  for (int s2=128; s2; s2>>=1){ if (tid<s2) redi[tid]+=redi[tid+s2]; __syncthreads(); }
  int code = 0;
  if (tid==0){
    if (redi[0] != 0) code |= 512;
    if (i0==UNK || (i0==EOS && t<=MIN_LEN)) code |= 512;
  }
  __syncthreads();
  redi[tid]=cg7; __syncthreads();
  for (int s2=128; s2; s2>>=1){ if (tid<s2) redi[tid]+=redi[tid+s2]; __syncthreads(); }
  if (tid==0){
    if (redi[0] > 7) code |= 1024;
    float sref = (v0 - rmax) - lsum;
    if (fabsf(sref - sc[TKSC_O + 0]) > 1e-4f) code |= 2048;
    if (code) atomicOr((int*)(sc + DIAG_O), code << shift);
  }
}

// ---------------- emit tokens (as float) + beam_scores ----------------
__global__ void emit_k(float* out, float* sc){
  int idx = blockIdx.x*256 + threadIdx.x;
  if (idx < T*N){
    out[TOK_OUT_OFF + idx] = (float)(((const int*)(sc + TOK1_O))[idx]);
    out[BS_OUT_OFF + idx]  = sc[BS1_O + idx];
  }
  if (idx == 0){
    int dc = ((const int*)(sc + DIAG_O))[0];
    if (dc) out[TOK_OUT_OFF] = 1.0e6f + (float)dc;
  }
}

extern "C" void kernel_launch(void* const* d_in, const int* in_sizes, int n_in,
                              void* d_out, int out_size, void* d_ws, size_t ws_size,
                              hipStream_t stream){
  const int*   src    = (const int*)d_in[0];
  const int*   srclen = (const int*)d_in[1];
  const float* embed  = (const float*)d_in[2];
  const float* eWih   = (const float*)d_in[3];
  const float* eWhh   = (const float*)d_in[4];
  const float* ebih   = (const float*)d_in[5];
  const float* ebhh   = (const float*)d_in[6];
  const float* brW    = (const float*)d_in[7];
  const float* brb    = (const float*)d_in[8];
  const float* dWih   = (const float*)d_in[9];
  const float* dWhh   = (const float*)d_in[10];
  const float* dbih   = (const float*)d_in[11];
  const float* dbhh   = (const float*)d_in[12];
  const float* attW   = (const float*)d_in[13];
  const float* cmbW   = (const float*)d_in[14];
  const float* cmbb   = (const float*)d_in[15];
  const float* outW   = (const float*)d_in[16];
  const float* outb   = (const float*)d_in[17];
  float* sc = (float*)d_out;

  tr_k<<<dim3(16,48),256,0,stream>>>(eWih, sc+WTEIH_O, 1536, 512);
  tr_k<<<dim3(16,48),256,0,stream>>>(eWhh, sc+WTEHH_O, 1536, 512);
  tr_k<<<dim3(16,48),256,0,stream>>>(dWih, sc+WTDIH_O, 1536, 512);
  tr_k<<<dim3(16,48),256,0,stream>>>(dWhh, sc+WTDHH_O, 1536, 512);
  tr_k<<<dim3(16,16),256,0,stream>>>(attW, sc+WTATT_O, 512, 512);
  tr_k<<<dim3(32,16),256,0,stream>>>(cmbW, sc+WTCMB_O, 512, 1024);
  tr_k<<<dim3(16,16),256,0,stream>>>(brW,  sc+WTBRG_O, 512, 512);
  tr_k<<<dim3(16,1000),256,0,stream>>>(outW, sc+WTOUT_O, 32000, 512);
  init_k<<<64,256,0,stream>>>(sc);

  for (int t=0; t<S; t++)
    enc_k<<<dim3(16,2),256,0,stream>>>(src, srclen, embed, sc+WTEIH_O, sc+WTEHH_O, ebih, ebhh, sc, t);
  bridge_k<<<16,256,0,stream>>>(sc+WTBRG_O, brb, sc);

  for (int t=1; t<T; t++){
    grudec_k<<<dim3(8,16),256,0,stream>>>(embed, sc+WTDIH_O, sc+WTDHH_O, dbih, dbhh, sc);
    qgemm_k<<<dim3(8,16),256,0,stream>>>(sc+WTATT_O, sc);
    att_k<<<128,256,0,stream>>>(srclen, sc);
    comb_k<<<dim3(8,16),256,0,stream>>>(sc+WTCMB_O, cmbb, sc);
    logits_k<<<dim3(125,8),256,0,stream>>>(sc+WTOUT_O, outb, sc);
    if (t==1 || t==5)
      diag_net_k<<<1,256,0,stream>>>(srclen, embed, dWih, dWhh, dbih, dbhh, attW, cmbW, cmbb, outW, outb, sc, (t==1)?0:12);
    topk_k<<<128,256,0,stream>>>(sc, t);
    if (t==1 || t==5)
      diag_topk_k<<<1,256,0,stream>>>(sc, t, (t==1)?0:12);
    beam_k<<<16,64,0,stream>>>(sc, t);
  }

  emit_k<<<20,256,0,stream>>>((float*)d_out, sc);
  hipMemsetAsync(d_out, 0, (size_t)PROBS_ELEMS*4, stream);
}

// Round 3
// 17880.521 us; speedup vs baseline: 1.1059x; 1.1059x over previous
//
#include <hip/hip_runtime.h>

#define DEVFN __device__ __forceinline__

constexpr int V=32000, E=512, H=512, B=16, K=8, S=50, T=40, N=128;
constexpr int SOS=2, EOS=3, UNK=0, PAD=1, MIN_LEN=3;
constexpr float DD=0.1f;
constexpr float FNEG=-1e20f;

constexpr long long PROBS_ELEMS = 163840000LL; // T*N*V
constexpr int TOK_OUT_OFF = 163840000;
constexpr int BS_OUT_OFF  = 163845120;

// scratch offsets (floats) inside d_out's probs region (re-zeroed at the end)
constexpr int LOGITS_O = 0;          // N*V = 4,096,000
constexpr int WTOUT_O  = 4200000;    // 512*32000
constexpr int WTEIH_O  = 20600000;   // 512*1536
constexpr int WTEHH_O  = 21400000;
constexpr int WTDIH_O  = 22200000;
constexpr int WTDHH_O  = 23000000;
constexpr int WTATT_O  = 23800000;   // 512*512
constexpr int WTCMB_O  = 24100000;   // 1024*512
constexpr int WTBRG_O  = 24700000;   // 512*512
constexpr int ENC_O    = 25000000;   // S*B*H
constexpr int HST_O    = 25500000;   // 2*B*H
constexpr int HID_O    = 25520000;   // N*H
constexpr int HNEW_O   = 25600000;   // N*H
constexpr int CTX_O    = 25680000;   // N*H
constexpr int OVEC_O   = 25760000;   // N*H
constexpr int QVEC_O   = 25840000;   // N*H
constexpr int TKSC_O   = 25920000;   // N*K
constexpr int TKIX_O   = 25930000;   // N*K ints
constexpr int TOK0_O   = 25940000;   // T*N ints
constexpr int TOK1_O   = 25950000;
constexpr int BS0_O    = 25960000;   // T*N floats
constexpr int BS1_O    = 25970000;
constexpr int END_O    = 25980000;   // N ints
constexpr int LTOK_O   = 25990000;   // N ints

DEVFN float sigm(float x){ return 1.0f/(1.0f + expf(-x)); }

// ---------------- transpose: in[R][C] -> out[C][R] ----------------
__global__ void tr_k(const float* __restrict__ in, float* __restrict__ out, int R, int C){
  __shared__ float t[32][33];
  int bx = blockIdx.x, by = blockIdx.y;
  int x = threadIdx.x & 31, y0 = threadIdx.x >> 5;
  for (int yy = y0; yy < 32; yy += 8){
    t[yy][x] = in[(long long)(by*32+yy)*C + bx*32 + x];
  }
  __syncthreads();
  for (int yy = y0; yy < 32; yy += 8){
    out[(long long)(bx*32+yy)*R + by*32 + x] = t[x][yy];
  }
}

// ---------------- init ----------------
__global__ void init_k(float* sc){
  int idx = blockIdx.x*256 + threadIdx.x;
  int* tok0 = (int*)(sc + TOK0_O);
  float* bs0 = sc + BS0_O;
  if (idx < T*N){
    tok0[idx] = (idx < N) ? SOS : 0;
    bs0[idx]  = (idx < N && (idx & 7)) ? FNEG : 0.0f;
  }
  if (idx < N){
    ((int*)(sc + END_O))[idx] = 0;
    ((int*)(sc + LTOK_O))[idx] = SOS;
  }
  if (idx < 2*B*H) sc[HST_O + idx] = 0.0f;
}

// ---------------- encoder one step ----------------
__global__ __launch_bounds__(256) void enc_k(const int* __restrict__ src, const int* __restrict__ srclen,
                      const float* __restrict__ embed,
                      const float* __restrict__ wtih, const float* __restrict__ wthh,
                      const float* __restrict__ bih, const float* __restrict__ bhh,
                      float* sc, int t){
  int b = blockIdx.x;
  int i = blockIdx.y*256 + threadIdx.x;
  __shared__ __align__(16) float e[512];
  __shared__ __align__(16) float hp[512];
  const float* hsrc = sc + HST_O + (t&1)*B*H + b*H;
  float* hdst = sc + HST_O + (((t&1)^1))*B*H + b*H;
  int tok = src[t*B + b];
  {
    int tid = threadIdx.x;
    ((float2*)e)[tid]  = ((const float2*)(embed + (long long)tok*E))[tid];
    ((float2*)hp)[tid] = ((const float2*)hsrc)[tid];
  }
  __syncthreads();
  float ar=0,az=0,an=0,hr=0,hz=0,hn=0;
  for (int k=0;k<512;k++){
    float ev = e[k], hv = hp[k];
    const float* wi = wtih + (long long)k*1536;
    const float* wh = wthh + (long long)k*1536;
    ar += ev*wi[i];      az += ev*wi[512+i];  an += ev*wi[1024+i];
    hr += hv*wh[i];      hz += hv*wh[512+i];  hn += hv*wh[1024+i];
  }
  float r = sigm(ar + bih[i] + hr + bhh[i]);
  float z = sigm(az + bih[512+i] + hz + bhh[512+i]);
  float nn = tanhf(an + bih[1024+i] + r*(hn + bhh[1024+i]));
  float hnew = (1.0f - z)*nn + z*hp[i];
  float hout = (t < srclen[b]) ? hnew : hp[i];
  hdst[i] = hout;
  sc[ENC_O + ((long long)t*B + b)*H + i] = hout;
}

// ---------------- bridge + repeat K ----------------
__global__ __launch_bounds__(256) void bridge_k(const float* __restrict__ wtb, const float* __restrict__ bb, float* sc){
  int b = blockIdx.x; int tid = threadIdx.x;
  __shared__ __align__(16) float hf[512];
  const float* hsrc = sc + HST_O + (S&1)*B*H + b*H;
  ((float2*)hf)[tid] = ((const float2*)hsrc)[tid];
  __syncthreads();
  for (int ii=0; ii<2; ii++){
    int i = tid + ii*256;
    float acc = bb[i];
    for (int k=0;k<512;k++) acc += hf[k]*wtb[(long long)k*512 + i];
    float hb = tanhf(acc);
    for (int q=0;q<K;q++) sc[HID_O + ((long long)(b*K+q))*H + i] = hb;
  }
}

// ---------------- decoder GRU (all beams tiled) ----------------
__global__ __launch_bounds__(256) void grudec_k(const float* __restrict__ embed,
     const float* __restrict__ wtih, const float* __restrict__ wthh,
     const float* __restrict__ bih, const float* __restrict__ bhh, float* sc){
  int il = threadIdx.x & 63, sub = threadIdx.x >> 6;
  int i = blockIdx.x*64 + il;
  int nb = blockIdx.y*8;
  __shared__ __align__(16) float e8[8][512];
  __shared__ __align__(16) float hp8[8][512];
  const int* ltok = (const int*)(sc + LTOK_O);
  for (int u = threadIdx.x; u < 8*128; u += 256){
    int r = u >> 7, c = u & 127;
    ((float4*)e8[r])[c]  = ((const float4*)(embed + (long long)ltok[nb+r]*E))[c];
    ((float4*)hp8[r])[c] = ((const float4*)(sc + HID_O + (long long)(nb+r)*H))[c];
  }
  __syncthreads();
  int n0 = sub*2, n1 = sub*2+1;
  float a0r=0,a0z=0,a0n=0,h0r=0,h0z=0,h0n=0;
  float a1r=0,a1z=0,a1n=0,h1r=0,h1z=0,h1n=0;
  for (int k=0;k<512;k++){
    const float* wi = wtih + (long long)k*1536;
    const float* wh = wthh + (long long)k*1536;
    float wr=wi[i], wz=wi[512+i], wn=wi[1024+i];
    float ur=wh[i], uz=wh[512+i], un=wh[1024+i];
    float e0=e8[n0][k], e1=e8[n1][k], p0=hp8[n0][k], p1=hp8[n1][k];
    a0r+=e0*wr; a0z+=e0*wz; a0n+=e0*wn; h0r+=p0*ur; h0z+=p0*uz; h0n+=p0*un;
    a1r+=e1*wr; a1z+=e1*wz; a1n+=e1*wn; h1r+=p1*ur; h1z+=p1*uz; h1n+=p1*un;
  }
  float br=bih[i], bz=bih[512+i], bn=bih[1024+i];
  float cr=bhh[i], cz=bhh[512+i], cn=bhh[1024+i];
  {
    float r = sigm(a0r+br+h0r+cr);
    float z = sigm(a0z+bz+h0z+cz);
    float nn = tanhf(a0n+bn + r*(h0n+cn));
    sc[HNEW_O + (long long)(nb+n0)*H + i] = (1.0f-z)*nn + z*hp8[n0][i];
  }
  {
    float r = sigm(a1r+br+h1r+cr);
    float z = sigm(a1z+bz+h1z+cz);
    float nn = tanhf(a1n+bn + r*(h1n+cn));
    sc[HNEW_O + (long long)(nb+n1)*H + i] = (1.0f-z)*nn + z*hp8[n1][i];
  }
}

// ---------------- q = h_new @ attn_W^T ----------------
__global__ __launch_bounds__(256) void qgemm_k(const float* __restrict__ wta, float* sc){
  int il = threadIdx.x & 63, sub = threadIdx.x >> 6;
  int i = blockIdx.x*64 + il;
  int nb = blockIdx.y*8;
  __shared__ __align__(16) float hn8[8][512];
  for (int u = threadIdx.x; u < 8*128; u += 256){
    int r = u>>7, c = u&127;
    ((float4*)hn8[r])[c] = ((const float4*)(sc + HNEW_O + (long long)(nb+r)*H))[c];
  }
  __syncthreads();
  int n0 = sub*2, n1 = n0+1;
  float a0=0, a1=0;
  for (int k=0;k<512;k++){
    float w = wta[(long long)k*512 + i];
    a0 += hn8[n0][k]*w; a1 += hn8[n1][k]*w;
  }
  sc[QVEC_O + (long long)(nb+n0)*H + i] = a0;
  sc[QVEC_O + (long long)(nb+n1)*H + i] = a1;
}

// ---------------- attention scores/softmax/ctx per beam ----------------
__global__ __launch_bounds__(256) void att_k(const int* __restrict__ srclen, float* sc){
  int n = blockIdx.x; int g = n >> 3;
  int tid = threadIdx.x, lane = tid & 63, wave = tid >> 6;
  __shared__ __align__(16) float ql[512];
  __shared__ float al[64];
  if (tid < 128) ((float4*)ql)[tid] = ((const float4*)(sc + QVEC_O + (long long)n*H))[tid];
  __syncthreads();
  const float* enc = sc + ENC_O;
  for (int s = wave; s < S; s += 4){
    const float* er = enc + ((long long)s*B + g)*H;
    float p = 0;
    #pragma unroll
    for (int j=0;j<8;j++) p += ql[lane + 64*j]*er[lane + 64*j];
    #pragma unroll
    for (int off=32; off; off>>=1) p += __shfl_xor(p, off, 64);
    if (lane==0) al[s] = p;
  }
  __syncthreads();
  if (wave==0){
    int len = srclen[g];
    float v = (lane < S && lane < len) ? al[lane] : -1e9f;
    float m = v;
    #pragma unroll
    for (int off=32; off; off>>=1) m = fmaxf(m, __shfl_xor(m, off, 64));
    float ee = (lane < S) ? expf(v - m) : 0.0f;
    float ssum = ee;
    #pragma unroll
    for (int off=32; off; off>>=1) ssum += __shfl_xor(ssum, off, 64);
    if (lane < S) al[lane] = ee/ssum;
  }
  __syncthreads();
  for (int ii=0; ii<2; ii++){
    int i = tid + ii*256;
    float acc = 0;
    for (int s=0;s<S;s++) acc += al[s]*enc[((long long)s*B+g)*H + i];
    sc[CTX_O + (long long)n*H + i] = acc;
  }
}

// ---------------- o = tanh([h,ctx] @ comb_W^T + b) ----------------
__global__ __launch_bounds__(256) void comb_k(const float* __restrict__ wtc, const float* __restrict__ cb, float* sc){
  int il = threadIdx.x & 63, sub = threadIdx.x >> 6;
  int i = blockIdx.x*64 + il;
  int nb = blockIdx.y*8;
  __shared__ __align__(16) float hn8[8][512];
  __shared__ __align__(16) float cx8[8][512];
  for (int u = threadIdx.x; u < 8*128; u += 256){
    int r = u>>7, c = u&127;
    ((float4*)hn8[r])[c] = ((const float4*)(sc + HNEW_O + (long long)(nb+r)*H))[c];
    ((float4*)cx8[r])[c] = ((const float4*)(sc + CTX_O + (long long)(nb+r)*H))[c];
  }
  __syncthreads();
  int n0 = sub*2, n1 = n0+1;
  float a0=cb[i], a1=cb[i];
  for (int k=0;k<512;k++){
    float w = wtc[(long long)k*512 + i];
    a0 += hn8[n0][k]*w; a1 += hn8[n1][k]*w;
  }
  for (int k=0;k<512;k++){
    float w = wtc[(long long)(512+k)*512 + i];
    a0 += cx8[n0][k]*w; a1 += cx8[n1][k]*w;
  }
  sc[OVEC_O + (long long)(nb+n0)*H + i] = tanhf(a0);
  sc[OVEC_O + (long long)(nb+n1)*H + i] = tanhf(a1);
}

// ---------------- logits = o @ out_W^T + out_b ----------------
// Block: 1024 v-cols (all 256 threads distinct v), 16 rows via 32KB LDS.
// Weight read 8x/step total (one per row-group), k-loop unrolled x4.
__global__ __launch_bounds__(256) void logits_k(const float* __restrict__ wto, const float* __restrict__ ob, float* sc){
  int v = blockIdx.x*1024 + threadIdx.x*4;
  int nb = blockIdx.y*16;
  __shared__ __align__(16) float o16[16][512];
  for (int u = threadIdx.x; u < 16*128; u += 256){
    int r = u>>7, c = u&127;
    ((float4*)o16[r])[c] = ((const float4*)(sc + OVEC_O + (long long)(nb + r)*H))[c];
  }
  __syncthreads();
  if (v >= V) return;
  float acc[16][4] = {};
  const float* wp = wto + v;
  for (int k=0;k<512;k+=4){
    float4 w0 = *((const float4*)(wp + (long long)(k+0)*V));
    float4 w1 = *((const float4*)(wp + (long long)(k+1)*V));
    float4 w2 = *((const float4*)(wp + (long long)(k+2)*V));
    float4 w3 = *((const float4*)(wp + (long long)(k+3)*V));
    #pragma unroll
    for (int j=0;j<16;j++){
      float4 o = *((const float4*)&o16[j][k]);
      acc[j][0] += o.x*w0.x + o.y*w1.x + o.z*w2.x + o.w*w3.x;
      acc[j][1] += o.x*w0.y + o.y*w1.y + o.z*w2.y + o.w*w3.y;
      acc[j][2] += o.x*w0.z + o.y*w1.z + o.z*w2.z + o.w*w3.z;
      acc[j][3] += o.x*w0.w + o.y*w1.w + o.z*w2.w + o.w*w3.w;
    }
  }
  float4 bbv = *((const float4*)(ob + v));
  #pragma unroll
  for (int j=0;j<16;j++){
    float4 r;
    r.x = acc[j][0]+bbv.x; r.y = acc[j][1]+bbv.y; r.z = acc[j][2]+bbv.z; r.w = acc[j][3]+bbv.w;
    *((float4*)(sc + LOGITS_O + (long long)(nb+j)*V + v)) = r;
  }
}

// ---------------- per-row logsumexp + top-8 in 2 passes ----------------
// Pass 1: raw max. Pass 2: raw sumexp + per-thread stable top-8 (static-index
// insertion, no scratch) + LDS tree merge keeping (val desc, idx asc) order.
__global__ __launch_bounds__(256) void topk_k(float* sc, int t){
  int n = blockIdx.x, tid = threadIdx.x;
  const float4* row4 = (const float4*)(sc + LOGITS_O + (long long)n*V);
  __shared__ float rv[256];
  __shared__ float mv[256][8];
  __shared__ int   mi[256][8];
  // pass 1: raw max
  float lm = -INFINITY;
  for (int u = tid; u < V/4; u += 256){
    float4 x = row4[u];
    lm = fmaxf(lm, fmaxf(fmaxf(x.x,x.y), fmaxf(x.z,x.w)));
  }
  rv[tid] = lm; __syncthreads();
  for (int s2=128; s2; s2>>=1){ if (tid<s2) rv[tid]=fmaxf(rv[tid],rv[tid+s2]); __syncthreads(); }
  float rmax = rv[0]; __syncthreads();
  // pass 2: raw sumexp + masked per-thread top-8
  float tv[8]; int ti[8];
  #pragma unroll
  for (int j=0;j<8;j++){ tv[j] = -INFINITY; ti[j] = V; }
  float ls = 0;
  for (int u = tid; u < V/4; u += 256){
    float4 x = row4[u];
    ls += expf(x.x-rmax)+expf(x.y-rmax)+expf(x.z-rmax)+expf(x.w-rmax);
    #pragma unroll
    for (int c=0;c<4;c++){
      int idx = u*4+c;
      float val = (c==0)?x.x:(c==1)?x.y:(c==2)?x.z:x.w;
      bool masked = (idx==UNK) || (idx==EOS && t<=MIN_LEN);
      if (!masked && val > tv[7]){
        tv[7] = val; ti[7] = idx;
        #pragma unroll
        for (int j=7;j>0;j--){
          if (tv[j] > tv[j-1]){
            float tf=tv[j]; tv[j]=tv[j-1]; tv[j-1]=tf;
            int tii=ti[j]; ti[j]=ti[j-1]; ti[j-1]=tii;
          }
        }
      }
    }
  }
  rv[tid] = ls;
  #pragma unroll
  for (int j=0;j<8;j++){ mv[tid][j]=tv[j]; mi[tid][j]=ti[j]; }
  __syncthreads();
  // sum reduce
  for (int s2=128; s2; s2>>=1){ if (tid<s2) rv[tid]+=rv[tid+s2]; __syncthreads(); }
  float lsum = logf(rv[0]);
  // tree merge of sorted-8 lists
  for (int s2=128; s2; s2>>=1){
    if (tid < s2){
      float ra[8]; int ri_[8];
      int pa=0, pb=0;
      #pragma unroll
      for (int o=0;o<8;o++){
        float va = mv[tid][pa<8?pa:7];   int xa = mi[tid][pa<8?pa:7];
        float vb = mv[tid+s2][pb<8?pb:7]; int xb = mi[tid+s2][pb<8?pb:7];
        bool ava = (pa<8), avb = (pb<8);
        bool ta;
        if (!ava) ta = false;
        else if (!avb) ta = true;
        else ta = (va > vb) || (va == vb && xa < xb);
        ra[o] = ta ? va : vb; ri_[o] = ta ? xa : xb;
        pa += ta ? 1 : 0; pb += ta ? 0 : 1;
      }
      #pragma unroll
      for (int o=0;o<8;o++){ mv[tid][o]=ra[o]; mi[tid][o]=ri_[o]; }
    }
    __syncthreads();
  }
  if (tid < 8){
    sc[TKSC_O + n*8 + tid] = (mv[0][tid] - rmax) - lsum;
    ((int*)(sc + TKIX_O))[n*8 + tid] = mi[0][tid];
  }
}

// ---------------- beam bookkeeping (serial on lane 0 of one wave per batch) ----------------
__global__ __launch_bounds__(64) void beam_k(float* sc, int t){
  int b = blockIdx.x, lane = threadIdx.x;
  const float* tksc = sc + TKSC_O;
  const int* tkix = (const int*)(sc + TKIX_O);
  int* endp = (int*)(sc + END_O);
  int* ltok = (int*)(sc + LTOK_O);
  const int* tokc; int* tokn; const float* bsc; float* bsn;
  if (t & 1){ tokc=(const int*)(sc+TOK0_O); tokn=(int*)(sc+TOK1_O); bsc=sc+BS0_O; bsn=sc+BS1_O; }
  else      { tokc=(const int*)(sc+TOK1_O); tokn=(int*)(sc+TOK0_O); bsc=sc+BS1_O; bsn=sc+BS0_O; }
  __shared__ int selp[8]; __shared__ int newtok[8]; __shared__ float newsc[8]; __shared__ int newend[8];
  if (lane == 0){
    float tot[64]; float cur[64]; int tix[64];
    for (int k=0;k<8;k++){
      float tp = 0;
      for (int u=0;u<T;u++) tp += bsc[u*N + b*8 + k];
      int ek = endp[b*8+k];
      for (int j=0;j<8;j++){
        float scv = tksc[(b*8+k)*8 + j];
        if (t > 1) scv -= DD * (float)j;
        float fin = ek ? (-scv + (j==0 ? 0.0f : FNEG)) : 0.0f;
        tot[k*8+j] = (scv + tp) + fin;   // ((tk_sc+total)+fin) as in ref
        cur[k*8+j] = scv + fin;
        tix[k*8+j] = tkix[(b*8+k)*8 + j];
      }
    }
    for (int q=0;q<8;q++){
      int best = 0; float bv = tot[0];
      for (int c=1;c<64;c++){
        if (tot[c] > bv){ bv = tot[c]; best = c; }   // strict > keeps lowest index on ties
      }
      int p = best >> 3;
      int en = endp[b*8+p];
      int tk2 = tix[best];
      int lt = en ? PAD : tk2;
      selp[q] = p;
      newtok[q] = lt;
      newsc[q] = (lt != PAD) ? cur[best] : 0.0f;
      newend[q] = (en || lt == EOS) ? 1 : 0;
      tot[best] = -INFINITY;
    }
  }
  __syncthreads();
  for (int u = lane; u < T*8; u += 64){
    int tp2 = u >> 3, jp = u & 7;
    int p = selp[jp];
    tokn[tp2*N + b*8 + jp] = tokc[tp2*N + b*8 + p];
    bsn[tp2*N + b*8 + jp]  = bsc[tp2*N + b*8 + p];
  }
  __syncthreads();
  if (lane < 8){
    tokn[t*N + b*8 + lane] = newtok[lane];
    bsn[t*N + b*8 + lane]  = newsc[lane];
    ltok[b*8+lane] = newtok[lane];
    endp[b*8+lane] = newend[lane];
  }
  // hidden = hidden[flat_offsets] (beam-0 broadcast of h_new within group)
  const float4* hsrc = (const float4*)(sc + HNEW_O + (long long)(b*8)*H);
  float4* hdst = (float4*)(sc + HID_O + (long long)(b*8)*H);
  for (int u = lane; u < 8*128; u += 64){
    int jp = u >> 7, c = u & 127;
    hdst[jp*128 + c] = hsrc[c];
  }
}

// ---------------- emit tokens (as float) + beam_scores ----------------
__global__ void emit_k(float* out, float* sc){
  int idx = blockIdx.x*256 + threadIdx.x;
  if (idx < T*N){
    out[TOK_OUT_OFF + idx] = (float)(((const int*)(sc + TOK1_O))[idx]);
    out[BS_OUT_OFF + idx]  = sc[BS1_O + idx];
  }
}

extern "C" void kernel_launch(void* const* d_in, const int* in_sizes, int n_in,
                              void* d_out, int out_size, void* d_ws, size_t ws_size,
                              hipStream_t stream){
  const int*   src    = (const int*)d_in[0];
  const int*   srclen = (const int*)d_in[1];
  const float* embed  = (const float*)d_in[2];
  const float* eWih   = (const float*)d_in[3];
  const float* eWhh   = (const float*)d_in[4];
  const float* ebih   = (const float*)d_in[5];
  const float* ebhh   = (const float*)d_in[6];
  const float* brW    = (const float*)d_in[7];
  const float* brb    = (const float*)d_in[8];
  const float* dWih   = (const float*)d_in[9];
  const float* dWhh   = (const float*)d_in[10];
  const float* dbih   = (const float*)d_in[11];
  const float* dbhh   = (const float*)d_in[12];
  const float* attW   = (const float*)d_in[13];
  const float* cmbW   = (const float*)d_in[14];
  const float* cmbb   = (const float*)d_in[15];
  const float* outW   = (const float*)d_in[16];
  const float* outb   = (const float*)d_in[17];
  float* sc = (float*)d_out;

  tr_k<<<dim3(16,48),256,0,stream>>>(eWih, sc+WTEIH_O, 1536, 512);
  tr_k<<<dim3(16,48),256,0,stream>>>(eWhh, sc+WTEHH_O, 1536, 512);
  tr_k<<<dim3(16,48),256,0,stream>>>(dWih, sc+WTDIH_O, 1536, 512);
  tr_k<<<dim3(16,48),256,0,stream>>>(dWhh, sc+WTDHH_O, 1536, 512);
  tr_k<<<dim3(16,16),256,0,stream>>>(attW, sc+WTATT_O, 512, 512);
  tr_k<<<dim3(32,16),256,0,stream>>>(cmbW, sc+WTCMB_O, 512, 1024);
  tr_k<<<dim3(16,16),256,0,stream>>>(brW,  sc+WTBRG_O, 512, 512);
  tr_k<<<dim3(16,1000),256,0,stream>>>(outW, sc+WTOUT_O, 32000, 512);
  init_k<<<64,256,0,stream>>>(sc);

  for (int t=0; t<S; t++)
    enc_k<<<dim3(16,2),256,0,stream>>>(src, srclen, embed, sc+WTEIH_O, sc+WTEHH_O, ebih, ebhh, sc, t);
  bridge_k<<<16,256,0,stream>>>(sc+WTBRG_O, brb, sc);

  for (int t=1; t<T; t++){
    grudec_k<<<dim3(8,16),256,0,stream>>>(embed, sc+WTDIH_O, sc+WTDHH_O, dbih, dbhh, sc);
    qgemm_k<<<dim3(8,16),256,0,stream>>>(sc+WTATT_O, sc);
    att_k<<<128,256,0,stream>>>(srclen, sc);
    comb_k<<<dim3(8,16),256,0,stream>>>(sc+WTCMB_O, cmbb, sc);
    logits_k<<<dim3(32,8),256,0,stream>>>(sc+WTOUT_O, outb, sc);
    topk_k<<<128,256,0,stream>>>(sc, t);
    beam_k<<<16,64,0,stream>>>(sc, t);
  }

  emit_k<<<20,256,0,stream>>>((float*)d_out, sc);
  hipMemsetAsync(d_out, 0, (size_t)PROBS_ELEMS*4, stream);
}